// Round 1
// baseline (508.171 us; speedup 1.0000x reference)
//
#include <hip/hip_runtime.h>
#include <hip/hip_fp16.h>

typedef _Float16 f16;
typedef _Float16 f16x8 __attribute__((ext_vector_type(8)));
typedef _Float16 f16x4 __attribute__((ext_vector_type(4)));
typedef float    f32x4 __attribute__((ext_vector_type(4)));

#define MFMA16(a, b, c) __builtin_amdgcn_mfma_f32_16x16x32_f16((a), (b), (c), 0, 0, 0)

__device__ __forceinline__ void gload16(const void* g, void* l) {
  __builtin_amdgcn_global_load_lds(
      (const __attribute__((address_space(1))) unsigned int*)g,
      (__attribute__((address_space(3))) unsigned int*)l,
      16, 0, 0);
}

// ---------------- f32 -> f16 cast (vectorized, 4 elems/thread) ----------------
__global__ __launch_bounds__(256) void cast_f32_to_f16(const float* __restrict__ src,
                                                       f16* __restrict__ dst, int n4) {
  int i = blockIdx.x * 256 + threadIdx.x;
  if (i >= n4) return;
  float4 v = reinterpret_cast<const float4*>(src)[i];
  f16x4 o = { (f16)v.x, (f16)v.y, (f16)v.z, (f16)v.w };
  reinterpret_cast<f16x4*>(dst)[i] = o;
}

// ---------------- GEMM: C[M,N] = A[M,K] * B[N,K]^T  (m97 structure) ----------------
// 128x128 tile, BK=32, 256 threads (4 waves, 2x2 of 64x64), 16x16x32 f16 MFMA.
template <typename OutT>
__global__ __launch_bounds__(256, 2) void gemm_bt(const f16* __restrict__ A,
                                                  const f16* __restrict__ B,
                                                  OutT* __restrict__ C,
                                                  int M, int N, int K) {
  __shared__ f16 sA[128 * 32];
  __shared__ f16 sB[128 * 32];
  const int tid = threadIdx.x;
  const int w = tid >> 6, l = tid & 63;
  const int wr = w >> 1, wc = w & 1;
  const int bx = blockIdx.x, by = blockIdx.y;

  const f16* Ag = A + (size_t)(by * 128 + (tid >> 2)) * K + (tid & 3) * 8;
  const f16* Bg = B + (size_t)(bx * 128 + (tid >> 2)) * K + (tid & 3) * 8;
  f16* sAw0 = sA + (w * 16) * 32;
  f16* sAw1 = sA + (64 + w * 16) * 32;
  f16* sBw0 = sB + (w * 16) * 32;
  f16* sBw1 = sB + (64 + w * 16) * 32;

  f32x4 acc[4][4] = {};

  for (int k0 = 0; k0 < K; k0 += 32) {
    gload16(Ag + k0, sAw0);
    gload16(Ag + (size_t)64 * K + k0, sAw1);
    gload16(Bg + k0, sBw0);
    gload16(Bg + (size_t)64 * K + k0, sBw1);
    __syncthreads();   // drains vmcnt(0) then barrier: LDS tiles ready

    f16x8 af[4], bf[4];
#pragma unroll
    for (int m = 0; m < 4; ++m)
      af[m] = *reinterpret_cast<const f16x8*>(sA + (wr * 64 + m * 16 + (l & 15)) * 32 + ((l >> 4) << 3));
#pragma unroll
    for (int n = 0; n < 4; ++n)
      bf[n] = *reinterpret_cast<const f16x8*>(sB + (wc * 64 + n * 16 + (l & 15)) * 32 + ((l >> 4) << 3));
#pragma unroll
    for (int m = 0; m < 4; ++m)
#pragma unroll
      for (int n = 0; n < 4; ++n)
        acc[m][n] = MFMA16(af[m], bf[n], acc[m][n]);
    __syncthreads();   // all waves done reading before next stage overwrites
  }

  const int r0 = by * 128 + wr * 64 + ((l >> 4) << 2);
  const int c0 = bx * 128 + wc * 64 + (l & 15);
#pragma unroll
  for (int m = 0; m < 4; ++m)
#pragma unroll
    for (int n = 0; n < 4; ++n)
#pragma unroll
      for (int j = 0; j < 4; ++j)
        C[(size_t)(r0 + m * 16 + j) * N + c0 + n * 16] = (OutT)acc[m][n][j];
}

// ---------------- scores + softmax ----------------
// One block per (b,h). L[kd,qd] = (1/8) * sum_y K[y,kd]*Q[y,qd]  (K=4096 reduction).
// Both operands staged TRANSPOSED in LDS as [d][y] (pad 72) so MFMA frag reads are
// contiguous b128. Softmax over qd (rows of L). Output Z^T: zt[bh][zq][kd] (f16).
__global__ __launch_bounds__(256, 2) void scores_softmax(const f16* __restrict__ qkv,
                                                         f16* __restrict__ zt) {
  const int bh = blockIdx.x;             // 0..127
  const int b = bh >> 4, h = bh & 15;
  const f16* qg = qkv + (size_t)b * 4096 * 3072 + h * 64;
  const f16* kg = qg + 1024;

  __shared__ f16 sQ[64 * 72];            // Qt[qd][y]
  __shared__ f16 sK[64 * 72];            // Kt[kd][y]
  __shared__ float sL[64 * 64];

  const int tid = threadIdx.x;
  const int w = tid >> 6, l = tid & 63;

  f32x4 acc[4] = {};                     // wave w owns kd rows [w*16, w*16+16)

  for (int y0 = 0; y0 < 4096; y0 += 64) {
    __syncthreads();                     // protect previous iter's reads
    // stage transposed: wave w loads d-chunks {2w, 2w+1}; lane l -> y = l
#pragma unroll
    for (int cc = 0; cc < 2; ++cc) {
      const int c = 2 * w + cc;
      f16x8 vq = *reinterpret_cast<const f16x8*>(qg + (size_t)(y0 + l) * 3072 + c * 8);
      f16x8 vk = *reinterpret_cast<const f16x8*>(kg + (size_t)(y0 + l) * 3072 + c * 8);
#pragma unroll
      for (int j = 0; j < 8; ++j) {
        sQ[(c * 8 + j) * 72 + l] = vq[j];   // consecutive lanes -> consecutive bytes: conflict-free
        sK[(c * 8 + j) * 72 + l] = vk[j];
      }
    }
    __syncthreads();
#pragma unroll
    for (int ks = 0; ks < 2; ++ks) {
      f16x8 a = *reinterpret_cast<const f16x8*>(sK + (w * 16 + (l & 15)) * 72 + ks * 32 + ((l >> 4) << 3));
#pragma unroll
      for (int n = 0; n < 4; ++n) {
        f16x8 bq = *reinterpret_cast<const f16x8*>(sQ + (n * 16 + (l & 15)) * 72 + ks * 32 + ((l >> 4) << 3));
        acc[n] = MFMA16(a, bq, acc[n]);
      }
    }
  }

  __syncthreads();
#pragma unroll
  for (int n = 0; n < 4; ++n)
#pragma unroll
    for (int j = 0; j < 4; ++j)
      sL[(w * 16 + ((l >> 4) << 2) + j) * 64 + n * 16 + (l & 15)] = acc[n][j] * 0.125f;
  __syncthreads();

  if (tid < 64) {                        // one thread per kd row; softmax over qd
    float mx = -1e30f;
    for (int q = 0; q < 64; ++q) mx = fmaxf(mx, sL[tid * 64 + q]);
    float s = 0.f;
    for (int q = 0; q < 64; ++q) {
      float e = __expf(sL[tid * 64 + q] - mx);
      sL[tid * 64 + q] = e;
      s += e;
    }
    float inv = 1.f / s;
    f16* dst = zt + (size_t)bh * 4096 + tid;   // store transposed: zt[zq*64 + kd]
    for (int q = 0; q < 64; ++q) dst[q * 64] = (f16)(sL[tid * 64 + q] * inv);
  }
}

// ---------------- PV + head merge ----------------
// out2[b*4096+s, h*64+zq] = sum_kd V[s,kd] * Z[kd,zq].  Per block: one (bh, 128-row s-tile).
__global__ __launch_bounds__(256, 2) void pv_merge(const f16* __restrict__ qkv,
                                                   const f16* __restrict__ zt,
                                                   f16* __restrict__ out2) {
  const int st = blockIdx.x;             // 0..31
  const int bh = blockIdx.y;             // 0..127
  const int b = bh >> 4, h = bh & 15;
  const f16* vg = qkv + (size_t)(b * 4096 + st * 128) * 3072 + 2048 + h * 64;

  __shared__ f16 sV[128 * 72];           // V[s][kd], pad 72
  __shared__ f16 sZ[64 * 72];            // Zt[zq][kd], pad 72

  const int tid = threadIdx.x;
  const int w = tid >> 6, l = tid & 63;

#pragma unroll
  for (int p = 0; p < 4; ++p) {
    int idx = (p * 256 + tid) * 8;
    int row = idx >> 6, col = idx & 63;
    f16x8 v = *reinterpret_cast<const f16x8*>(vg + (size_t)row * 3072 + col);
    *reinterpret_cast<f16x8*>(sV + row * 72 + col) = v;
  }
#pragma unroll
  for (int p = 0; p < 2; ++p) {
    int idx = (p * 256 + tid) * 8;
    int row = idx >> 6, col = idx & 63;
    f16x8 v = *reinterpret_cast<const f16x8*>(zt + (size_t)bh * 4096 + idx);
    *reinterpret_cast<f16x8*>(sZ + row * 72 + col) = v;
  }
  __syncthreads();

  f32x4 acc[2][4] = {};
#pragma unroll
  for (int ks = 0; ks < 2; ++ks) {
    f16x8 av[2], bz[4];
#pragma unroll
    for (int m = 0; m < 2; ++m)
      av[m] = *reinterpret_cast<const f16x8*>(sV + (w * 32 + m * 16 + (l & 15)) * 72 + ks * 32 + ((l >> 4) << 3));
#pragma unroll
    for (int n = 0; n < 4; ++n)
      bz[n] = *reinterpret_cast<const f16x8*>(sZ + (n * 16 + (l & 15)) * 72 + ks * 32 + ((l >> 4) << 3));
#pragma unroll
    for (int m = 0; m < 2; ++m)
#pragma unroll
      for (int n = 0; n < 4; ++n)
        acc[m][n] = MFMA16(av[m], bz[n], acc[m][n]);
  }

#pragma unroll
  for (int m = 0; m < 2; ++m)
#pragma unroll
    for (int n = 0; n < 4; ++n)
#pragma unroll
      for (int j = 0; j < 4; ++j) {
        int s = st * 128 + w * 32 + m * 16 + ((l >> 4) << 2) + j;
        out2[(size_t)(b * 4096 + s) * 1024 + h * 64 + n * 16 + (l & 15)] = (f16)acc[m][n][j];
      }
}

// ---------------- launch ----------------
extern "C" void kernel_launch(void* const* d_in, const int* in_sizes, int n_in,
                              void* d_out, int out_size, void* d_ws, size_t ws_size,
                              hipStream_t stream) {
  const float* x  = (const float*)d_in[0];
  const float* Wq = (const float*)d_in[1];
  const float* Wk = (const float*)d_in[2];
  const float* Wv = (const float*)d_in[3];
  const float* Wo = (const float*)d_in[4];
  float* out = (float*)d_out;

  // workspace carve (halves):
  f16* xh    = (f16*)d_ws;               //  33,554,432  x (f16)
  f16* qkvh  = xh + 33554432;            // 100,663,296  [32768 x 3072] q|k|v
  f16* wqkvh = qkvh + 100663296;         //   3,145,728  [3072 x 1024]
  f16* woh   = wqkvh + 3145728;          //   1,048,576  [1024 x 1024]
  f16* zth   = woh + 1048576;            //     524,288  [128][64 zq][64 kd]
  f16* out2h = zth + 524288;             //  33,554,432  [32768 x 1024] merged
  // total = 344,981,504 bytes

  cast_f32_to_f16<<<32768, 256, 0, stream>>>(x, xh, 33554432 / 4);
  cast_f32_to_f16<<<1024, 256, 0, stream>>>(Wq, wqkvh, 1048576 / 4);
  cast_f32_to_f16<<<1024, 256, 0, stream>>>(Wk, wqkvh + 1048576, 1048576 / 4);
  cast_f32_to_f16<<<1024, 256, 0, stream>>>(Wv, wqkvh + 2097152, 1048576 / 4);
  cast_f32_to_f16<<<1024, 256, 0, stream>>>(Wo, woh, 1048576 / 4);

  // QKV projection: [32768,3072] = xh * Wqkv^T
  gemm_bt<f16><<<dim3(24, 256), 256, 0, stream>>>(xh, wqkvh, qkvh, 32768, 3072, 1024);

  // 64x64 scores over sequence axis + softmax -> Z^T
  scores_softmax<<<128, 256, 0, stream>>>(qkvh, zth);

  // out2 = V * Z, merged heads
  pv_merge<<<dim3(32, 128), 256, 0, stream>>>(qkvh, zth, out2h);

  // output projection: d_out = out2 * Wo^T (f32 out)
  gemm_bt<float><<<dim3(8, 256), 256, 0, stream>>>(out2h, woh, out, 32768, 1024, 1024);
}